// Round 3
// baseline (1657.369 us; speedup 1.0000x reference)
//
#include <hip/hip_runtime.h>
#include <stdint.h>

// Problem constants (B, D, L, K from the reference). fp32 I/O per reference.
#define NB 4096
#define DD 2048
#define LL 16384
#define KT 64
#define WCAP 16        // window candidate cap per row
#define TAU 3e-4f      // refinement window half-width (>>3e-5 zhat error bound)

typedef unsigned short u16;
typedef __bf16 bf16x8 __attribute__((ext_vector_type(8)));
typedef float f32x4 __attribute__((ext_vector_type(4)));
typedef unsigned short u16x4 __attribute__((ext_vector_type(4)));

__device__ __forceinline__ float bf2f(u16 b) {
  return __uint_as_float(((unsigned)b) << 16);
}
__device__ __forceinline__ u16 f2bf(float f) {
  unsigned u = __float_as_uint(f);
  unsigned r = u + 0x7fffu + ((u >> 16) & 1u);  // RNE
  return (u16)(r >> 16);
}

// ---------------------------------------------------------------------------
// Kernel 1: split X fp32 -> X_hi, X_lo bf16 (x = hi + lo + O(2^-18 x))
// ---------------------------------------------------------------------------
__global__ __launch_bounds__(256) void prep_x(const float* __restrict__ X,
                                              u16* __restrict__ Xh,
                                              u16* __restrict__ Xl) {
  int i = (blockIdx.x * 256 + threadIdx.x) * 4;
  float4 v = *(const float4*)(X + i);
  u16x4 h, l;
  float f[4] = {v.x, v.y, v.z, v.w};
#pragma unroll
  for (int q = 0; q < 4; ++q) {
    u16 hb = f2bf(f[q]);
    h[q] = hb;
    l[q] = f2bf(f[q] - bf2f(hb));
  }
  *(u16x4*)(Xh + i) = h;
  *(u16x4*)(Xl + i) = l;
}

// ---------------------------------------------------------------------------
// Kernel 2: transpose + split W fp32 [2048,16384] -> Wt_hi/Wt_lo bf16 [16384,2048]
// ---------------------------------------------------------------------------
__global__ __launch_bounds__(256) void prep_w(const float* __restrict__ W,
                                              u16* __restrict__ Wh,
                                              u16* __restrict__ Wl) {
  __shared__ float tile[64][65];  // +1 pad breaks write-phase bank aliasing
  int l0 = blockIdx.x * 64, d0 = blockIdx.y * 64;
  int t = threadIdx.x;
  int lx = (t & 15) * 4;  // 4 consecutive l -> float4 global loads (16B aligned)
  int dq = t >> 4;
#pragma unroll
  for (int p = 0; p < 4; ++p) {
    int d = dq + p * 16;
    float4 v = *(const float4*)(W + (size_t)(d0 + d) * LL + l0 + lx);
    tile[d][lx + 0] = v.x; tile[d][lx + 1] = v.y;
    tile[d][lx + 2] = v.z; tile[d][lx + 3] = v.w;
  }
  __syncthreads();
  int dx = (t & 15) * 4;
  int lq = t >> 4;
#pragma unroll
  for (int p = 0; p < 4; ++p) {
    int l = lq + p * 16;
    u16x4 h, lo;
#pragma unroll
    for (int q = 0; q < 4; ++q) {
      float w = tile[dx + q][l];
      u16 hb = f2bf(w);
      h[q] = hb;
      lo[q] = f2bf(w - bf2f(hb));
    }
    size_t o = (size_t)(l0 + l) * DD + d0 + dx;  // 8B-aligned (dx mult of 4)
    *(u16x4*)(Wh + o) = h;
    *(u16x4*)(Wl + o) = lo;
  }
}

// ---------------------------------------------------------------------------
// Kernel 3: split-precision encode GEMM (m97 structure, 3 MFMAs/frag-pair):
//   Z ~= Xh·Wh^T + Xh·Wl^T + Xl·Wh^T  (+ benc)   error sigma ~ 7e-6
// 128x128 tile, BK=32, 4 waves of 64x64, global_load_lds w=16, ds_read_b128.
// ---------------------------------------------------------------------------
#define BM 128
#define BN 128
#define BK 32

__device__ __forceinline__ void async16(const u16* g, u16* l) {
  __builtin_amdgcn_global_load_lds(
      (const __attribute__((address_space(1))) unsigned int*)g,
      (__attribute__((address_space(3))) unsigned int*)l, 16, 0, 0);
}

__global__ __launch_bounds__(256) void encode_gemm(
    const u16* __restrict__ Xh, const u16* __restrict__ Xl,  // [rows,2048] (pre-offset)
    const u16* __restrict__ Wh, const u16* __restrict__ Wl,  // [16384,2048]
    const float* __restrict__ benc,                          // [16384] fp32
    float* __restrict__ Z) {                                 // [rows,16384]
  __shared__ u16 Ash[BM * BK], Asl[BM * BK];  // 8 KB each
  __shared__ u16 Bsh[BN * BK], Bsl[BN * BK];  // total LDS 32 KB
  int t = threadIdx.x;
  int m0 = blockIdx.y * BM;
  int n0 = blockIdx.x * BN;

  int w = t >> 6, lane = t & 63;
  int wm = (w & 1) * 64, wn = (w >> 1) * 64;
  int fr = lane & 15;
  int fq = lane >> 4;

  f32x4 acc[4][4] = {};

  const u16* xh = Xh + (size_t)m0 * DD;
  const u16* xl = Xl + (size_t)m0 * DD;
  const u16* bh = Wh + (size_t)n0 * DD;
  const u16* bl = Wl + (size_t)n0 * DD;

  for (int k0 = 0; k0 < DD; k0 += BK) {
#pragma unroll
    for (int p = 0; p < 2; ++p) {
      int c = p * 256 + t;
      int r = c >> 2;
      int ko = (c & 3) * 8;
      size_t go = (size_t)r * DD + k0 + ko;
      async16(xh + go, Ash + c * 8);
      async16(xl + go, Asl + c * 8);
      async16(bh + go, Bsh + c * 8);
      async16(bl + go, Bsl + c * 8);
    }
    __syncthreads();  // vmcnt(0) drain before barrier (compiler-emitted)

    bf16x8 ah[4], al[4], bhf[4], blf[4];
#pragma unroll
    for (int i = 0; i < 4; ++i) {
      int ao = (wm + i * 16 + fr) * BK + fq * 8;
      int bo = (wn + i * 16 + fr) * BK + fq * 8;
      ah[i]  = *(const bf16x8*)(Ash + ao);
      al[i]  = *(const bf16x8*)(Asl + ao);
      bhf[i] = *(const bf16x8*)(Bsh + bo);
      blf[i] = *(const bf16x8*)(Bsl + bo);
    }
#pragma unroll
    for (int i = 0; i < 4; ++i)
#pragma unroll
      for (int j = 0; j < 4; ++j) {
        acc[i][j] = __builtin_amdgcn_mfma_f32_16x16x32_bf16(ah[i], bhf[j], acc[i][j], 0, 0, 0);
        acc[i][j] = __builtin_amdgcn_mfma_f32_16x16x32_bf16(ah[i], blf[j], acc[i][j], 0, 0, 0);
        acc[i][j] = __builtin_amdgcn_mfma_f32_16x16x32_bf16(al[i], bhf[j], acc[i][j], 0, 0, 0);
      }
    __syncthreads();
  }

  // C/D layout: col = lane&15, row = (lane>>4)*4 + reg  [m89/m91]
  int rbase = m0 + wm + fq * 4;
#pragma unroll
  for (int j = 0; j < 4; ++j) {
    int col = n0 + wn + j * 16 + fr;
    float be = benc[col];
#pragma unroll
    for (int i = 0; i < 4; ++i) {
      int row = rbase + i * 16;
#pragma unroll
      for (int r = 0; r < 4; ++r)
        Z[(size_t)(row + r) * LL + col] = acc[i][j][r] + be;
    }
  }
}

// ---------------------------------------------------------------------------
// Kernel 4: per-row exact top-64 of |zhat| via bitwise radix descent on fp32
// bit patterns; classify "sure" (key > cut+TAU: in top-64 regardless of the
// ~3e-5 zhat error) vs "window" ([cut-TAU, cut+TAU]: deferred to fp64 fixup).
// Zeros z_sparse row, scatters sure values, records window candidates.
// ---------------------------------------------------------------------------
__global__ __launch_bounds__(256) void topk_kernel(
    const float* __restrict__ Z,    // [rows,16384] chunk
    float* __restrict__ ZS,         // z_sparse chunk base (fp32)
    int* __restrict__ TKI, float* __restrict__ TKV,   // global, row-indexed
    int* __restrict__ WIDX, int* __restrict__ META,   // global, row-indexed
    int r0) {
  int lrow = blockIdx.x, grow = r0 + lrow, t = threadIdx.x;
  const float* zr = Z + (size_t)lrow * LL;
  float* zs = ZS + (size_t)lrow * LL;

  uint4 kv[16];  // |zhat| bit keys, 64 per thread
#pragma unroll
  for (int i = 0; i < 16; ++i) {
    float4 v = ((const float4*)zr)[t + i * 256];
    kv[i].x = __float_as_uint(v.x) & 0x7fffffffu;
    kv[i].y = __float_as_uint(v.y) & 0x7fffffffu;
    kv[i].z = __float_as_uint(v.z) & 0x7fffffffu;
    kv[i].w = __float_as_uint(v.w) & 0x7fffffffu;
  }
  float4 z4 = {0.f, 0.f, 0.f, 0.f};
#pragma unroll
  for (int i = 0; i < 16; ++i) ((float4*)zs)[t + i * 256] = z4;

  __shared__ int red[4];
  unsigned cut = 0;  // ends as exact 64th-largest key
  for (int bit = 30; bit >= 0; --bit) {
    unsigned ct = cut | (1u << bit);
    int cnt = 0;
#pragma unroll
    for (int i = 0; i < 16; ++i)
      cnt += (kv[i].x >= ct) + (kv[i].y >= ct) + (kv[i].z >= ct) + (kv[i].w >= ct);
    for (int off = 32; off > 0; off >>= 1) cnt += __shfl_down(cnt, off, 64);
    if ((t & 63) == 0) red[t >> 6] = cnt;
    __syncthreads();
    int total = red[0] + red[1] + red[2] + red[3];
    if (total >= KT) cut = ct;
    __syncthreads();
  }

  float cutf = __uint_as_float(cut);
  float chi = cutf + TAU;
  float clo = cutf - TAU; if (clo < 0.f) clo = 0.f;
  unsigned hiKey = __float_as_uint(chi);
  unsigned loKey = __float_as_uint(clo);

  __shared__ unsigned nsel, ntie;
  if (t == 0) { nsel = 0; ntie = 0; }
  __syncthreads();

#pragma unroll
  for (int i = 0; i < 16; ++i) {
    int base = 4 * (t + i * 256);
    unsigned k4[4] = {kv[i].x, kv[i].y, kv[i].z, kv[i].w};
#pragma unroll
    for (int q = 0; q < 4; ++q) {
      unsigned key = k4[q];
      int idx = base + q;
      if (key > hiKey) {  // sure: count(>cut+TAU) <= count(>cut) <= 63
        unsigned p = atomicAdd(&nsel, 1u);
        if (p < KT) {
          float v = zr[idx];  // signed zhat
          TKI[grow * KT + p] = idx;
          TKV[grow * KT + p] = v;
          zs[idx] = v;
        }
      } else if (key >= loKey) {  // window candidate
        unsigned p = atomicAdd(&ntie, 1u);
        if (p < WCAP) WIDX[grow * WCAP + p] = idx;
      }
    }
  }
  __syncthreads();
  if (t == 0) {
    int ns = (int)nsel; if (ns > KT) ns = KT;
    int wc = (int)ntie; if (wc > WCAP) wc = WCAP;
    META[grow * 2 + 0] = ns;
    META[grow * 2 + 1] = wc;
  }
}

// ---------------------------------------------------------------------------
// Kernel 5: fixup — fill the remaining (64 - nsure) slots from the window.
// Uncontested (wcnt == deferred): take all, zhat values. Contested: exact fp64
// dots x·W[:,idx]+benc (strided column gather from original W — rare rows
// only), rank by (|z| desc, idx asc) to match np top_k tie order.
// ---------------------------------------------------------------------------
__global__ __launch_bounds__(256) void fixup_kernel(
    const float* __restrict__ X32, const float* __restrict__ W,
    const float* __restrict__ benc, const float* __restrict__ Z,
    float* __restrict__ ZS, const int* __restrict__ WIDX,
    const int* __restrict__ META, int* __restrict__ TKI,
    float* __restrict__ TKV, int r0) {
  int lrow = blockIdx.x, grow = r0 + lrow, t = threadIdx.x;
  int nsure = META[grow * 2 + 0];
  int wcnt = META[grow * 2 + 1];
  int deferred = KT - nsure;
  if (deferred <= 0) return;              // uniform exit
  if (deferred > wcnt) deferred = wcnt;   // safety (shouldn't trigger)

  __shared__ int widx[WCAP];
  __shared__ double wz[WCAP];
  __shared__ double wr[4];
  if (t < wcnt) widx[t] = WIDX[grow * WCAP + t];
  __syncthreads();

  if (wcnt == deferred) {  // uncontested: all window items selected
    if (t < wcnt) {
      int idx = widx[t];
      float v = Z[(size_t)lrow * LL + idx];
      TKI[grow * KT + nsure + t] = idx;
      TKV[grow * KT + nsure + t] = v;
      ZS[(size_t)lrow * LL + idx] = v;
    }
    return;
  }

  __shared__ float xs[DD];
  for (int i = t; i < DD; i += 256) xs[i] = X32[(size_t)grow * DD + i];
  __syncthreads();
  for (int j = 0; j < wcnt; ++j) {
    int idx = widx[j];
    double p = 0.0;
    for (int k = t; k < DD; k += 256)
      p += (double)xs[k] * (double)W[(size_t)k * LL + idx];
    for (int off = 32; off > 0; off >>= 1) p += __shfl_down(p, off, 64);
    if ((t & 63) == 0) wr[t >> 6] = p;
    __syncthreads();
    if (t == 0) wz[j] = wr[0] + wr[1] + wr[2] + wr[3] + (double)benc[idx];
    __syncthreads();
  }
  if (t == 0) {
    int taken = 0;  // bitmask over wcnt (<=16)
    for (int s = 0; s < deferred; ++s) {
      int best = -1; double bv = -1.0;
      for (int j = 0; j < wcnt; ++j) {
        if (taken & (1 << j)) continue;
        double a = fabs(wz[j]);
        if (best < 0 || a > bv || (a == bv && widx[j] < widx[best])) {
          best = j; bv = a;
        }
      }
      taken |= (1 << best);
      int idx = widx[best];
      float v = (float)wz[best];
      TKI[grow * KT + nsure + s] = idx;
      TKV[grow * KT + nsure + s] = v;
      ZS[(size_t)lrow * LL + idx] = v;
    }
  }
}

// ---------------------------------------------------------------------------
// Kernel 6: decode  recon[b,d] = b_dec[d] + sum_j val_j * Wt_hi[idx_j, d]
// bf16 Wt_hi gather (recon error ~6e-4 << 0.121 threshold), fp32 accum/out.
// ---------------------------------------------------------------------------
__global__ __launch_bounds__(256) void decode_kernel(
    const u16* __restrict__ Wh, const float* __restrict__ bdec,
    const int* __restrict__ TKI, const float* __restrict__ TKV,
    float* __restrict__ OUT) {
  int row = blockIdx.x, t = threadIdx.x;
  typedef unsigned short u16x8 __attribute__((ext_vector_type(8)));
  __shared__ int sidx[KT];
  __shared__ float sval[KT];
  if (t < KT) {
    sidx[t] = TKI[row * KT + t] & (LL - 1);
    sval[t] = TKV[row * KT + t];
  }
  __syncthreads();
  int d0 = t * 8;
  float acc[8] = {0.f, 0.f, 0.f, 0.f, 0.f, 0.f, 0.f, 0.f};
#pragma unroll 4
  for (int j = 0; j < KT; ++j) {
    const u16x8 wv = *(const u16x8*)(Wh + (size_t)sidx[j] * DD + d0);
    float v = sval[j];
#pragma unroll
    for (int e = 0; e < 8; ++e) acc[e] = fmaf(v, bf2f(wv[e]), acc[e]);
  }
  float4 o0, o1;
  o0.x = acc[0] + bdec[d0 + 0]; o0.y = acc[1] + bdec[d0 + 1];
  o0.z = acc[2] + bdec[d0 + 2]; o0.w = acc[3] + bdec[d0 + 3];
  o1.x = acc[4] + bdec[d0 + 4]; o1.y = acc[5] + bdec[d0 + 5];
  o1.z = acc[6] + bdec[d0 + 6]; o1.w = acc[7] + bdec[d0 + 7];
  float* dst = OUT + (size_t)row * DD + d0;
  *(float4*)dst = o0;
  *(float4*)(dst + 4) = o1;
}

// ---------------------------------------------------------------------------
// ws layout (fixed 170,164,224 B + adaptive fp32 Z chunk):
//  [Xh 16M][Xl 16M][Wh 64M][Wl 64M][TKI 1M][TKV 1M][WIDX 256K][META 32K][Zc..]
// Chunk count depends only on ws_size -> identical launches every call.
// ---------------------------------------------------------------------------
extern "C" void kernel_launch(void* const* d_in, const int* in_sizes, int n_in,
                              void* d_out, int out_size, void* d_ws,
                              size_t ws_size, hipStream_t stream) {
  const float* X = (const float*)d_in[0];     // [4096, 2048] fp32
  const float* W = (const float*)d_in[1];     // [2048, 16384] fp32
  const float* benc = (const float*)d_in[2];  // [16384] fp32
  const float* bdec = (const float*)d_in[3];  // [2048] fp32
  // d_in[4] = k (=64), compile-time constant here

  char* ws = (char*)d_ws;
  const size_t XH_B = (size_t)NB * DD * 2;      // 16,777,216
  const size_t WH_B = (size_t)LL * DD * 2;      // 67,108,864
  const size_t TKI_B = (size_t)NB * KT * 4;     // 1,048,576
  const size_t WIDX_B = (size_t)NB * WCAP * 4;  // 262,144
  const size_t META_B = (size_t)NB * 2 * 4;     // 32,768
  u16* Xh = (u16*)ws;
  u16* Xl = (u16*)(ws + XH_B);
  u16* Wh = (u16*)(ws + 2 * XH_B);
  u16* Wl = (u16*)(ws + 2 * XH_B + WH_B);
  int* TKI = (int*)(ws + 2 * XH_B + 2 * WH_B);
  float* TKV = (float*)(ws + 2 * XH_B + 2 * WH_B + TKI_B);
  int* WIDX = (int*)(ws + 2 * XH_B + 2 * WH_B + 2 * TKI_B);
  int* META = (int*)(ws + 2 * XH_B + 2 * WH_B + 2 * TKI_B + WIDX_B);
  float* Zc = (float*)(ws + 2 * XH_B + 2 * WH_B + 2 * TKI_B + WIDX_B + META_B);

  size_t fixed = 2 * XH_B + 2 * WH_B + 2 * TKI_B + WIDX_B + META_B;
  size_t avail = (ws_size > fixed) ? (ws_size - fixed) : 0;
  int chunk = (int)(avail / ((size_t)LL * 4));
  chunk = (chunk / BM) * BM;
  if (chunk > NB) chunk = NB;
  if (chunk < BM) chunk = BM;

  float* out_recon = (float*)d_out;                    // [4096, 2048]
  float* out_zs = (float*)d_out + (size_t)NB * DD;     // [4096, 16384]

  prep_x<<<NB * DD / 1024, 256, 0, stream>>>(X, Xh, Xl);
  prep_w<<<dim3(LL / 64, DD / 64), 256, 0, stream>>>(W, Wh, Wl);
  for (int r0 = 0; r0 < NB; r0 += chunk) {
    int rows = NB - r0; if (rows > chunk) rows = chunk;
    encode_gemm<<<dim3(LL / BN, rows / BM), 256, 0, stream>>>(
        Xh + (size_t)r0 * DD, Xl + (size_t)r0 * DD, Wh, Wl, benc, Zc);
    topk_kernel<<<rows, 256, 0, stream>>>(
        Zc, out_zs + (size_t)r0 * LL, TKI, TKV, WIDX, META, r0);
    fixup_kernel<<<rows, 256, 0, stream>>>(
        X, W, benc, Zc, out_zs + (size_t)r0 * LL, WIDX, META, TKI, TKV, r0);
  }
  decode_kernel<<<NB, 256, 0, stream>>>(Wh, bdec, TKI, TKV, out_recon);
}

// Round 4
// 1297.198 us; speedup vs baseline: 1.2777x; 1.2777x over previous
//
#include <hip/hip_runtime.h>
#include <stdint.h>

// Problem constants (B, D, L, K from the reference). fp32 I/O per reference.
#define NB 4096
#define DD 2048
#define LL 16384
#define KT 64
#define WCAP 24        // window candidate cap per row
#define TAU 1.2e-2f    // sure/window margin: 5.7 sigma of zhat error (hh-only)
#define T3 1e-4f       // tier-3 exact-fp64 gap threshold (matches round-3 exposure)

typedef unsigned short u16;
typedef __bf16 bf16x8 __attribute__((ext_vector_type(8)));
typedef float f32x4 __attribute__((ext_vector_type(4)));
typedef unsigned short u16x4 __attribute__((ext_vector_type(4)));
typedef unsigned short u16x8 __attribute__((ext_vector_type(8)));

__device__ __forceinline__ float bf2f(u16 b) {
  return __uint_as_float(((unsigned)b) << 16);
}
__device__ __forceinline__ u16 f2bf(float f) {
  unsigned u = __float_as_uint(f);
  unsigned r = u + 0x7fffu + ((u >> 16) & 1u);  // RNE
  return (u16)(r >> 16);
}

// ---------------------------------------------------------------------------
// Kernel 1: X fp32 -> Xh bf16 (hi part only; fixup reads fp32 X directly)
// ---------------------------------------------------------------------------
__global__ __launch_bounds__(256) void prep_x(const float* __restrict__ X,
                                              u16* __restrict__ Xh) {
  int i = (blockIdx.x * 256 + threadIdx.x) * 4;
  float4 v = *(const float4*)(X + i);
  u16x4 h;
  h[0] = f2bf(v.x); h[1] = f2bf(v.y); h[2] = f2bf(v.z); h[3] = f2bf(v.w);
  *(u16x4*)(Xh + i) = h;
}

// ---------------------------------------------------------------------------
// Kernel 2: transpose + split W fp32 [2048,16384] -> Wh/Wl bf16 [16384,2048]
// Wh feeds the GEMM + decode; Wh+Wl (w to ~4e-8 abs) feeds the mid-tier fixup.
// ---------------------------------------------------------------------------
__global__ __launch_bounds__(256) void prep_w(const float* __restrict__ W,
                                              u16* __restrict__ Wh,
                                              u16* __restrict__ Wl) {
  __shared__ float tile[64][65];  // +1 pad breaks write-phase bank aliasing
  int l0 = blockIdx.x * 64, d0 = blockIdx.y * 64;
  int t = threadIdx.x;
  int lx = (t & 15) * 4;
  int dq = t >> 4;
#pragma unroll
  for (int p = 0; p < 4; ++p) {
    int d = dq + p * 16;
    float4 v = *(const float4*)(W + (size_t)(d0 + d) * LL + l0 + lx);
    tile[d][lx + 0] = v.x; tile[d][lx + 1] = v.y;
    tile[d][lx + 2] = v.z; tile[d][lx + 3] = v.w;
  }
  __syncthreads();
  int dx = (t & 15) * 4;
  int lq = t >> 4;
#pragma unroll
  for (int p = 0; p < 4; ++p) {
    int l = lq + p * 16;
    u16x4 h, lo;
#pragma unroll
    for (int q = 0; q < 4; ++q) {
      float w = tile[dx + q][l];
      u16 hb = f2bf(w);
      h[q] = hb;
      lo[q] = f2bf(w - bf2f(hb));
    }
    size_t o = (size_t)(l0 + l) * DD + d0 + dx;
    *(u16x4*)(Wh + o) = h;
    *(u16x4*)(Wl + o) = lo;
  }
}

// ---------------------------------------------------------------------------
// Kernel 3: encode GEMM  zhat = Xh·Wh^T + benc  (single MFMA — pure m97
// structure: 128x128 tile, BK=32, 4 waves of 64x64, global_load_lds w=16,
// ds_read_b128 fragments). zhat error sigma ~2.1e-3, absorbed by TAU window.
// ---------------------------------------------------------------------------
#define BM 128
#define BN 128
#define BK 32

__device__ __forceinline__ void async16(const u16* g, u16* l) {
  __builtin_amdgcn_global_load_lds(
      (const __attribute__((address_space(1))) unsigned int*)g,
      (__attribute__((address_space(3))) unsigned int*)l, 16, 0, 0);
}

__global__ __launch_bounds__(256) void encode_gemm(
    const u16* __restrict__ Xh,   // [rows,2048] (pre-offset to chunk)
    const u16* __restrict__ Wh,   // [16384,2048]
    const float* __restrict__ benc,
    float* __restrict__ Z) {      // [rows,16384]
  __shared__ u16 As[BM * BK];  // 8 KB
  __shared__ u16 Bs[BN * BK];  // 8 KB
  int t = threadIdx.x;
  int m0 = blockIdx.y * BM;
  int n0 = blockIdx.x * BN;

  int w = t >> 6, lane = t & 63;
  int wm = (w & 1) * 64, wn = (w >> 1) * 64;
  int fr = lane & 15;
  int fq = lane >> 4;

  f32x4 acc[4][4] = {};

  const u16* xg = Xh + (size_t)m0 * DD;
  const u16* bg = Wh + (size_t)n0 * DD;

  for (int k0 = 0; k0 < DD; k0 += BK) {
#pragma unroll
    for (int p = 0; p < 2; ++p) {
      int c = p * 256 + t;
      int r = c >> 2;
      int ko = (c & 3) * 8;
      size_t go = (size_t)r * DD + k0 + ko;
      async16(xg + go, As + c * 8);
      async16(bg + go, Bs + c * 8);
    }
    __syncthreads();

    bf16x8 af[4], bfr[4];
#pragma unroll
    for (int i = 0; i < 4; ++i) {
      af[i]  = *(const bf16x8*)(As + (wm + i * 16 + fr) * BK + fq * 8);
      bfr[i] = *(const bf16x8*)(Bs + (wn + i * 16 + fr) * BK + fq * 8);
    }
#pragma unroll
    for (int i = 0; i < 4; ++i)
#pragma unroll
      for (int j = 0; j < 4; ++j)
        acc[i][j] = __builtin_amdgcn_mfma_f32_16x16x32_bf16(af[i], bfr[j],
                                                            acc[i][j], 0, 0, 0);
    __syncthreads();
  }

  // C/D layout: col = lane&15, row = (lane>>4)*4 + reg  [m89/m91]
  int rbase = m0 + wm + fq * 4;
#pragma unroll
  for (int j = 0; j < 4; ++j) {
    int col = n0 + wn + j * 16 + fr;
    float be = benc[col];
#pragma unroll
    for (int i = 0; i < 4; ++i) {
      int row = rbase + i * 16;
#pragma unroll
      for (int r = 0; r < 4; ++r)
        Z[(size_t)(row + r) * LL + col] = acc[i][j][r] + be;
    }
  }
}

// ---------------------------------------------------------------------------
// Kernel 4: per-row top-64 classify on |zhat|. 15-round radix descent on the
// TOP 16 BITS of the fp32 bit pattern (the cut bucket's sub-ulp ambiguity is
// absorbed by the TAU window). sure: |zhat| > bucket_hi + TAU (provably <=63
// of these). window: |zhat| in [bucket_lo - TAU, bucket_hi + TAU] -> fixup.
// Zeros z_sparse row, scatters sure values, pre-fills remaining slots with 0.
// ---------------------------------------------------------------------------
__global__ __launch_bounds__(256) void topk_kernel(
    const float* __restrict__ Z, float* __restrict__ ZS,
    int* __restrict__ TKI, float* __restrict__ TKV,
    int* __restrict__ WIDX, int* __restrict__ META, int r0) {
  int lrow = blockIdx.x, grow = r0 + lrow, t = threadIdx.x;
  const float* zr = Z + (size_t)lrow * LL;
  float* zs = ZS + (size_t)lrow * LL;

  uint4 kv[16];  // |zhat| bit keys, 64 per thread
#pragma unroll
  for (int i = 0; i < 16; ++i) {
    float4 v = ((const float4*)zr)[t + i * 256];
    kv[i].x = __float_as_uint(v.x) & 0x7fffffffu;
    kv[i].y = __float_as_uint(v.y) & 0x7fffffffu;
    kv[i].z = __float_as_uint(v.z) & 0x7fffffffu;
    kv[i].w = __float_as_uint(v.w) & 0x7fffffffu;
  }
  float4 z4 = {0.f, 0.f, 0.f, 0.f};
#pragma unroll
  for (int i = 0; i < 16; ++i) ((float4*)zs)[t + i * 256] = z4;

  __shared__ int red[4];
  unsigned cut = 0;  // prefix over bits 30..16; low 16 bits stay 0
  for (int bit = 30; bit >= 16; --bit) {
    unsigned ct = cut | (1u << bit);
    int cnt = 0;
#pragma unroll
    for (int i = 0; i < 16; ++i)
      cnt += (kv[i].x >= ct) + (kv[i].y >= ct) + (kv[i].z >= ct) + (kv[i].w >= ct);
    for (int off = 32; off > 0; off >>= 1) cnt += __shfl_down(cnt, off, 64);
    if ((t & 63) == 0) red[t >> 6] = cnt;
    __syncthreads();
    int total = red[0] + red[1] + red[2] + red[3];
    if (total >= KT) cut = ct;
    __syncthreads();
  }

  // cut bucket = [c16, cnx); true zhat-rank-64 lies inside it.
  float c16 = __uint_as_float(cut);
  float cnx = __uint_as_float(cut + 0x10000u);
  float chi = cnx + TAU;
  float clo = c16 - TAU; if (clo < 0.f) clo = 0.f;
  unsigned hiKey = __float_as_uint(chi);
  unsigned loKey = (clo > 0.f) ? __float_as_uint(clo) : 0u;

  __shared__ unsigned nsel, ntie;
  if (t == 0) { nsel = 0; ntie = 0; }
  __syncthreads();

#pragma unroll
  for (int i = 0; i < 16; ++i) {
    int base = 4 * (t + i * 256);
    unsigned k4[4] = {kv[i].x, kv[i].y, kv[i].z, kv[i].w};
#pragma unroll
    for (int q = 0; q < 4; ++q) {
      unsigned key = k4[q];
      int idx = base + q;
      if (key > hiKey) {  // sure: count(> bucket_hi + TAU) <= 63 by radix invariant
        unsigned p = atomicAdd(&nsel, 1u);
        if (p < KT) {
          float v = zr[idx];
          TKI[grow * KT + p] = idx;
          TKV[grow * KT + p] = v;
          zs[idx] = v;
        }
      } else if (key >= loKey) {
        unsigned p = atomicAdd(&ntie, 1u);
        if (p < WCAP) WIDX[grow * WCAP + p] = idx;
      }
    }
  }
  __syncthreads();
  int ns = (int)nsel; if (ns > KT) ns = KT;
  // insurance: pre-fill deferred slots with idx=0/val=0 (fixup overwrites;
  // if the window ever under-covers, decode sees benign zeros, not poison)
  if (t >= ns && t < KT) { TKI[grow * KT + t] = 0; TKV[grow * KT + t] = 0.f; }
  if (t == 0) {
    int wc = (int)ntie; if (wc > WCAP) wc = WCAP;
    META[grow * 2 + 0] = ns;
    META[grow * 2 + 1] = wc;
  }
}

// ---------------------------------------------------------------------------
// Kernel 5: fixup — fill the (64 - nsure) remaining slots from the window.
// Tier 2 (mid): fp64 dot from contiguous split rows x_fp32 · (Wh+Wl), error
// sigma ~1.7e-6 (coalesced). Tier 3: exact fp64 via strided fp32 W columns,
// only for candidates within T3 of the selection boundary (rare) — keeps the
// np-fp32-vs-fp64 tie exposure identical to the passing round-3 run.
// Rank by (|z| desc, idx asc) to match np top_k order.
// ---------------------------------------------------------------------------
__global__ __launch_bounds__(256) void fixup_kernel(
    const float* __restrict__ X32, const float* __restrict__ W,
    const float* __restrict__ benc, const u16* __restrict__ Wh,
    const u16* __restrict__ Wl, const float* __restrict__ Z,
    float* __restrict__ ZS, const int* __restrict__ WIDX,
    const int* __restrict__ META, int* __restrict__ TKI,
    float* __restrict__ TKV, int r0) {
  int lrow = blockIdx.x, grow = r0 + lrow, t = threadIdx.x;
  int nsure = META[grow * 2 + 0];
  int wcnt = META[grow * 2 + 1];
  int deferred = KT - nsure;
  if (deferred <= 0) return;              // uniform exit per block
  if (deferred > wcnt) deferred = wcnt;   // safety (tau violation; degrade soft)

  __shared__ int widx[WCAP];
  if (t < wcnt) widx[t] = WIDX[grow * WCAP + t];
  __syncthreads();

  if (wcnt == deferred) {  // uncontested: take all (zhat values)
    if (t < wcnt) {
      int idx = widx[t];
      float v = Z[(size_t)lrow * LL + idx];
      TKI[grow * KT + nsure + t] = idx;
      TKV[grow * KT + nsure + t] = v;
      ZS[(size_t)lrow * LL + idx] = v;
    }
    return;
  }

  // contested: mid-tier recompute for all candidates
  __shared__ float xs[DD];
  __shared__ double wz[WCAP];
  __shared__ double wr[4];
  __shared__ int exact_flag[WCAP];
  for (int i = t; i < DD; i += 256) xs[i] = X32[(size_t)grow * DD + i];
  __syncthreads();
  for (int j = 0; j < wcnt; ++j) {
    int idx = widx[j];
    const u16* wh = Wh + (size_t)idx * DD;
    const u16* wl = Wl + (size_t)idx * DD;
    double p = 0.0;
    for (int k = t; k < DD; k += 256)
      p += (double)xs[k] * ((double)bf2f(wh[k]) + (double)bf2f(wl[k]));
    for (int off = 32; off > 0; off >>= 1) p += __shfl_down(p, off, 64);
    if ((t & 63) == 0) wr[t >> 6] = p;
    __syncthreads();
    if (t == 0) wz[j] = wr[0] + wr[1] + wr[2] + wr[3] + (double)benc[idx];
    __syncthreads();
  }

  // tier-3 marking: boundary = deferred-th largest |wz|; flag near-boundary
  if (t == 0) {
    int taken = 0;
    double b = 0.0;
    for (int s = 0; s < deferred; ++s) {
      int best = -1; double bv = -1.0;
      for (int j = 0; j < wcnt; ++j) {
        if (taken & (1 << j)) continue;
        double a = fabs(wz[j]);
        if (best < 0 || a > bv || (a == bv && widx[j] < widx[best])) { best = j; bv = a; }
      }
      taken |= (1 << best);
      b = bv;
    }
    for (int j = 0; j < wcnt; ++j)
      exact_flag[j] = (fabs(fabs(wz[j]) - b) < (double)T3) ? 1 : 0;
  }
  __syncthreads();
  for (int j = 0; j < wcnt; ++j) {
    if (!exact_flag[j]) continue;  // uniform per block (shared flag)
    int idx = widx[j];
    double p = 0.0;
    for (int k = t; k < DD; k += 256)
      p += (double)xs[k] * (double)W[(size_t)k * LL + idx];
    for (int off = 32; off > 0; off >>= 1) p += __shfl_down(p, off, 64);
    if ((t & 63) == 0) wr[t >> 6] = p;
    __syncthreads();
    if (t == 0) wz[j] = wr[0] + wr[1] + wr[2] + wr[3] + (double)benc[idx];
    __syncthreads();
  }

  if (t == 0) {
    int taken = 0;
    for (int s = 0; s < deferred; ++s) {
      int best = -1; double bv = -1.0;
      for (int j = 0; j < wcnt; ++j) {
        if (taken & (1 << j)) continue;
        double a = fabs(wz[j]);
        if (best < 0 || a > bv || (a == bv && widx[j] < widx[best])) { best = j; bv = a; }
      }
      taken |= (1 << best);
      int idx = widx[best];
      float v = (float)wz[best];
      TKI[grow * KT + nsure + s] = idx;
      TKV[grow * KT + nsure + s] = v;
      ZS[(size_t)lrow * LL + idx] = v;
    }
  }
}

// ---------------------------------------------------------------------------
// Kernel 6: decode  recon[b,d] = b_dec[d] + sum_j val_j * Wh[idx_j, d]
// (Wh-only: error ~7e-4 << bf16-ulp comparison granularity; round-3 verified)
// ---------------------------------------------------------------------------
__global__ __launch_bounds__(256) void decode_kernel(
    const u16* __restrict__ Wh, const float* __restrict__ bdec,
    const int* __restrict__ TKI, const float* __restrict__ TKV,
    float* __restrict__ OUT) {
  int row = blockIdx.x, t = threadIdx.x;
  __shared__ int sidx[KT];
  __shared__ float sval[KT];
  if (t < KT) {
    sidx[t] = TKI[row * KT + t] & (LL - 1);
    sval[t] = TKV[row * KT + t];
  }
  __syncthreads();
  int d0 = t * 8;
  float acc[8] = {0.f, 0.f, 0.f, 0.f, 0.f, 0.f, 0.f, 0.f};
#pragma unroll 4
  for (int j = 0; j < KT; ++j) {
    const u16x8 wv = *(const u16x8*)(Wh + (size_t)sidx[j] * DD + d0);
    float v = sval[j];
#pragma unroll
    for (int e = 0; e < 8; ++e) acc[e] = fmaf(v, bf2f(wv[e]), acc[e]);
  }
  float4 o0, o1;
  o0.x = acc[0] + bdec[d0 + 0]; o0.y = acc[1] + bdec[d0 + 1];
  o0.z = acc[2] + bdec[d0 + 2]; o0.w = acc[3] + bdec[d0 + 3];
  o1.x = acc[4] + bdec[d0 + 4]; o1.y = acc[5] + bdec[d0 + 5];
  o1.z = acc[6] + bdec[d0 + 6]; o1.w = acc[7] + bdec[d0 + 7];
  float* dst = OUT + (size_t)row * DD + d0;
  *(float4*)dst = o0;
  *(float4*)(dst + 4) = o1;
}

// ---------------------------------------------------------------------------
// ws layout (fixed ~153.5 MB + adaptive fp32 Z chunk):
//  [Xh 16M][Wh 64M][Wl 64M][TKI 1M][TKV 1M][WIDX 384K][META 32K][Zc ...]
// ---------------------------------------------------------------------------
extern "C" void kernel_launch(void* const* d_in, const int* in_sizes, int n_in,
                              void* d_out, int out_size, void* d_ws,
                              size_t ws_size, hipStream_t stream) {
  const float* X = (const float*)d_in[0];     // [4096, 2048] fp32
  const float* W = (const float*)d_in[1];     // [2048, 16384] fp32
  const float* benc = (const float*)d_in[2];  // [16384] fp32
  const float* bdec = (const float*)d_in[3];  // [2048] fp32

  char* ws = (char*)d_ws;
  const size_t XH_B = (size_t)NB * DD * 2;      // 16,777,216
  const size_t WH_B = (size_t)LL * DD * 2;      // 67,108,864
  const size_t TKI_B = (size_t)NB * KT * 4;     // 1,048,576
  const size_t WIDX_B = (size_t)NB * WCAP * 4;  // 393,216
  const size_t META_B = (size_t)NB * 2 * 4;     // 32,768
  u16* Xh = (u16*)ws;
  u16* Wh = (u16*)(ws + XH_B);
  u16* Wl = (u16*)(ws + XH_B + WH_B);
  int* TKI = (int*)(ws + XH_B + 2 * WH_B);
  float* TKV = (float*)(ws + XH_B + 2 * WH_B + TKI_B);
  int* WIDX = (int*)(ws + XH_B + 2 * WH_B + 2 * TKI_B);
  int* META = (int*)(ws + XH_B + 2 * WH_B + 2 * TKI_B + WIDX_B);
  float* Zc = (float*)(ws + XH_B + 2 * WH_B + 2 * TKI_B + WIDX_B + META_B);

  size_t fixed = XH_B + 2 * WH_B + 2 * TKI_B + WIDX_B + META_B;
  size_t avail = (ws_size > fixed) ? (ws_size - fixed) : 0;
  int chunk = (int)(avail / ((size_t)LL * 4));
  chunk = (chunk / BM) * BM;
  if (chunk > NB) chunk = NB;
  if (chunk < BM) chunk = BM;

  float* out_recon = (float*)d_out;                    // [4096, 2048]
  float* out_zs = (float*)d_out + (size_t)NB * DD;     // [4096, 16384]

  prep_x<<<NB * DD / 1024, 256, 0, stream>>>(X, Xh);
  prep_w<<<dim3(LL / 64, DD / 64), 256, 0, stream>>>(W, Wh, Wl);
  for (int r0 = 0; r0 < NB; r0 += chunk) {
    int rows = NB - r0; if (rows > chunk) rows = chunk;
    encode_gemm<<<dim3(LL / BN, rows / BM), 256, 0, stream>>>(
        Xh + (size_t)r0 * DD, Wh, benc, Zc);
    topk_kernel<<<rows, 256, 0, stream>>>(
        Zc, out_zs + (size_t)r0 * LL, TKI, TKV, WIDX, META, r0);
    fixup_kernel<<<rows, 256, 0, stream>>>(
        X, W, benc, Wh, Wl, Zc, out_zs + (size_t)r0 * LL, WIDX, META, TKI,
        TKV, r0);
  }
  decode_kernel<<<NB, 256, 0, stream>>>(Wh, bdec, TKI, TKV, out_recon);
}